// Round 9
// baseline (524.440 us; speedup 1.0000x reference)
//
#include <hip/hip_runtime.h>
#include <hip/hip_bf16.h>

#define SS 32
#define EE 64
#define DD 256
#define LL 5

// DIAGNOSTIC ROUND: internal replication to surface per-kernel rocprof rows
// above the harness's ~76us fill dispatches. Idempotent + deterministic.
#define R_K2 6
#define R_K1 12
#define R_KB 16
#define R_KC 16

typedef unsigned int uint32;

static __device__ __forceinline__ int opaque_zero() {
    int z = 0;
    asm volatile("" : "+v"(z));   // compiler must assume z unknown -> no CSE across reps
    return z;
}

static __device__ __forceinline__ ushort f2bf(float f) {
    uint32 u = __float_as_uint(f);
    uint32 r = (u + 0x7FFFu + ((u >> 16) & 1u)) >> 16;   // RNE
    return (ushort)r;
}
static __device__ __forceinline__ float bf2f(ushort h) {
    return __uint_as_float(((uint32)h) << 16);
}

template <int CTRL>
static __device__ __forceinline__ float dpp_add(float x) {
    int y = __builtin_amdgcn_update_dpp(0, __float_as_int(x), CTRL, 0xF, 0xF, true);
    return x + __int_as_float(y);
}
static __device__ __forceinline__ float red16(float x) {
    x = dpp_add<0xB1>(x);    // xor 1
    x = dpp_add<0x4E>(x);    // xor 2
    x = dpp_add<0x141>(x);   // xor 7 (row_half_mirror)
    x = dpp_add<0x140>(x);   // xor 15 (row_mirror)
    return x;
}

// ws layout (f32 units):
//   pa 0 (1280) | pb 1280 (1280) | pa2 2560 | pb2 2565 | cvec 2570
//   cc 2576 (1280) | cc2 3856 | xself 4096 | xw 528384 (bf16)
//   wt 790528 | da 1445888 | db 1497088

// ================= K0: setup (15 blocks, x1) ===============================
__global__ __launch_bounds__(256) void k0_setup(
    const float* __restrict__ sup_entities,
    const float* __restrict__ sup_context,
    const int*   __restrict__ counts,
    float* __restrict__ ws) {
    int b = blockIdx.x;
    int t = threadIdx.x, lane = t & 63, wv = t >> 6;
    __shared__ float part[4];

    if (b < 10) {
        int k = (b >= 5) ? b - 5 : b;
        int off = (b >= 5) ? 256 : 0;
        float s = 0.f;
#pragma unroll
        for (int j = 0; j < 5; j++) s += sup_entities[(k * 5 + j) * 512 + off + t];
        float m = s * 0.2f;
        ws[(b >= 5 ? 1280 : 0) + k * 256 + t] = m;
        float p = m * m;
#pragma unroll
        for (int o = 1; o < 64; o <<= 1) p += __shfl_xor(p, o);
        if (lane == 0) part[wv] = p;
        __syncthreads();
        if (t == 0) ws[2560 + b] = part[0] + part[1] + part[2] + part[3];
    } else {
        int k = b - 10;
        float s = 0.f;
#pragma unroll
        for (int j = 0; j < 5; j++) s += sup_context[(k * 5 + j) * DD + t];
        float m = s * 0.2f;
        ws[2576 + k * 256 + t] = m;
        float p = m * m;
#pragma unroll
        for (int o = 1; o < 64; o <<= 1) p += __shfl_xor(p, o);
        if (lane == 0) part[wv] = p;
        __syncthreads();
        if (t == 0) ws[3856 + k] = part[0] + part[1] + part[2] + part[3];
        if (b == 10 && t == 1) {
            float cnt[5], tot = 0.f;
#pragma unroll
            for (int q = 0; q < 5; q++) { cnt[q] = (float)counts[q] + 1.0f; tot += cnt[q]; }
#pragma unroll
            for (int q = 0; q < 5; q++) ws[2570 + q] = cnt[q] / (tot - cnt[q]);
        }
    }
}

// ================= K1: xW + xself (x R_K1) =================================
__global__ __attribute__((amdgpu_waves_per_eu(2, 2))) __launch_bounds__(256)
void k1_gemm(
    const float* __restrict__ x_in, const float* __restrict__ W_in,
    const float* __restrict__ Ws_in, float* __restrict__ ws_in) {
    int row0 = blockIdx.x * 8;
    int t = threadIdx.x, lane = t & 63, wv = t >> 6;
    __shared__ float4 redbuf[4][8][64];   // 32 KB

#pragma unroll 1
    for (int rep = 0; rep < R_K1; rep++) {
        int oz = opaque_zero();
        const float* x = x_in + oz;
        const float* W = W_in + oz;
        const float* Wself = Ws_in + oz;
        float* ws = ws_in + oz;
        float* xself = ws + 4096;
        ushort* xw = (ushort*)(ws + 528384);
        __syncthreads();

        float xreg[8];
        const float* xbase = x + row0 * DD + wv * 64 + lane;
#pragma unroll
        for (int r = 0; r < 8; r++) xreg[r] = xbase[r * DD];

        float4 accW[8], accS[8];
#pragma unroll
        for (int r = 0; r < 8; r++) {
            accW[r] = make_float4(0.f, 0.f, 0.f, 0.f);
            accS[r] = make_float4(0.f, 0.f, 0.f, 0.f);
        }
        const float4* Wp  = ((const float4*)W) + lane;
        const float4* Wsp = ((const float4*)Wself) + lane;
#pragma unroll 2
        for (int i = 0; i < 64; i++) {
            int kk = wv * 64 + i;
            float4 w4  = Wp[kk * 64];
            float4 ws4 = Wsp[kk * 64];
#pragma unroll
            for (int r = 0; r < 8; r++) {
                float xs = __uint_as_float(
                    (uint32)__builtin_amdgcn_readlane((int)__float_as_uint(xreg[r]), i));
                accW[r].x = fmaf(xs, w4.x, accW[r].x);
                accW[r].y = fmaf(xs, w4.y, accW[r].y);
                accW[r].z = fmaf(xs, w4.z, accW[r].z);
                accW[r].w = fmaf(xs, w4.w, accW[r].w);
                accS[r].x = fmaf(xs, ws4.x, accS[r].x);
                accS[r].y = fmaf(xs, ws4.y, accS[r].y);
                accS[r].z = fmaf(xs, ws4.z, accS[r].z);
                accS[r].w = fmaf(xs, ws4.w, accS[r].w);
            }
        }
#pragma unroll
        for (int r = 0; r < 8; r++) redbuf[wv][r][lane] = accS[r];
        __syncthreads();
        {
            int r = t >> 5;
#pragma unroll
            for (int f = 0; f < 2; f++) {
                int l4 = (t & 31) + 32 * f;
                float4 a = redbuf[0][r][l4], b = redbuf[1][r][l4];
                float4 c = redbuf[2][r][l4], d = redbuf[3][r][l4];
                float4 s4 = make_float4(a.x + b.x + c.x + d.x, a.y + b.y + c.y + d.y,
                                        a.z + b.z + c.z + d.z, a.w + b.w + c.w + d.w);
                *(float4*)&xself[(row0 + r) * DD + l4 * 4] = s4;
            }
        }
        __syncthreads();
#pragma unroll
        for (int r = 0; r < 8; r++) redbuf[wv][r][lane] = accW[r];
        __syncthreads();
        {
            int r = t >> 5;
#pragma unroll
            for (int f = 0; f < 2; f++) {
                int l4 = (t & 31) + 32 * f;
                float4 a = redbuf[0][r][l4], b = redbuf[1][r][l4];
                float4 c = redbuf[2][r][l4], d = redbuf[3][r][l4];
                float4 s4 = make_float4(a.x + b.x + c.x + d.x, a.y + b.y + c.y + d.y,
                                        a.z + b.z + c.z + d.z, a.w + b.w + c.w + d.w);
                ushort4 h;
                h.x = f2bf(s4.x); h.y = f2bf(s4.y); h.z = f2bf(s4.z); h.w = f2bf(s4.w);
                *(ushort4*)&xw[(row0 + r) * DD + l4 * 4] = h;
            }
        }
    }
}

// ================= K2: context distances -> w (x R_K2) =====================
__global__ __attribute__((amdgpu_waves_per_eu(4, 4))) __launch_bounds__(256)
void k2_w(const float* __restrict__ ctx_in, float* __restrict__ ws_in) {
    int bx = blockIdx.x;
    int s = bx >> 6, u = bx & 63;
    int t = threadIdx.x, lane = t & 63, wv = t >> 6;
    int g = lane >> 4, gl = lane & 15;
    int G = wv * 4 + g;   // 0..15

    __shared__ float cc_l[1280];
    __shared__ float cc2_l[8];
    __shared__ float wbuf[5][64];

#pragma unroll 1
    for (int rep = 0; rep < R_K2; rep++) {
        int oz = opaque_zero();
        const float* context = ctx_in + oz;
        float* ws = ws_in + oz;
        float* wt = ws + 790528;
        __syncthreads();

        for (int i = t; i < 320; i += 256)
            ((float4*)cc_l)[i] = ((const float4*)(ws + 2576))[i];
        if (t < 5) cc2_l[t] = ws[3856 + t];
        __syncthreads();

        float4 cc[5][4];
        float cc2r[5];
#pragma unroll
        for (int k = 0; k < 5; k++) {
#pragma unroll
            for (int j = 0; j < 4; j++)
                cc[k][j] = *(const float4*)&cc_l[k * 256 + j * 64 + gl * 4];
            cc2r[k] = cc2_l[k];
        }

        const float* base = context + (size_t)bx * (EE * DD) + gl * 4;
#pragma unroll
        for (int p = 0; p < 4; p++) {
            int v = p * 16 + G;
            const float* row = base + v * DD;
            float4 a[4];
#pragma unroll
            for (int j = 0; j < 4; j++) a[j] = *(const float4*)&row[j * 64];

            float cn = 0.f;
            float cr[5] = {0.f, 0.f, 0.f, 0.f, 0.f};
#pragma unroll
            for (int j = 0; j < 4; j++) {
                float4 c4 = a[j];
                cn = fmaf(c4.x, c4.x, fmaf(c4.y, c4.y, fmaf(c4.z, c4.z, fmaf(c4.w, c4.w, cn))));
#pragma unroll
                for (int k = 0; k < 5; k++) {
                    float4 pp = cc[k][j];
                    cr[k] = fmaf(c4.x, pp.x, fmaf(c4.y, pp.y, fmaf(c4.z, pp.z, fmaf(c4.w, pp.w, cr[k]))));
                }
            }
            cn = red16(cn);
#pragma unroll
            for (int k = 0; k < 5; k++) cr[k] = red16(cr[k]);
            if (gl == 0) {
#pragma unroll
                for (int k = 0; k < 5; k++) {
                    float d2 = cn - 2.f * cr[k] + cc2r[k];
                    wbuf[k][v] = (u == v) ? 0.f : 1.f / fmaxf(d2, 1e-8f);
                }
            }
        }
        __syncthreads();
        for (int i = t; i < 320; i += 256) {
            int k = i >> 6, v = i & 63;
            wt[(((size_t)s * 5 + k) * 64 + u) * 64 + v] = wbuf[k][v];
        }
    }
}

// ================= K_B: out + distance dots (x R_KB) =======================
__global__ __attribute__((amdgpu_waves_per_eu(2, 2))) __launch_bounds__(256)
void kB(const float* __restrict__ ws_in) {
    int bx = blockIdx.x;
    int s = bx >> 4, vg = bx & 15;
    int t = threadIdx.x, lane = t & 63, wv = t >> 6;

    __shared__ ushort xw_l[64][256];   // 32 KB
    __shared__ float  w_l[5][64][4];   // 5 KB

#pragma unroll 1
    for (int rep = 0; rep < R_KB; rep++) {
        int oz = opaque_zero();
        const float* ws = ws_in + oz;
        const ushort* xw = (const ushort*)(ws + 528384);
        const float* xself = ws + 4096;
        const float* wt = ws + 790528;
        float* da = (float*)(ws + 1445888);
        float* db = (float*)(ws + 1497088);
        __syncthreads();

        {
            const uint4* src = (const uint4*)(xw + (size_t)s * (EE * DD));
            uint4* dst = (uint4*)&xw_l[0][0];
#pragma unroll
            for (int j = 0; j < 8; j++) dst[j * 256 + t] = src[j * 256 + t];
        }
        for (int i = t; i < 320; i += 256) {
            int k = i >> 6, u = i & 63;
            *(float4*)&w_l[k][u][0] =
                *(const float4*)&wt[(((size_t)s * 5 + k) * 64 + u) * 64 + vg * 4];
        }
        __syncthreads();

        int v = vg * 4 + wv;
        float4 acc[5];
        {
            float4 xs = *(const float4*)&xself[((size_t)s * 64 + v) * DD + lane * 4];
#pragma unroll
            for (int k = 0; k < 5; k++) acc[k] = xs;
        }

#pragma unroll 4
        for (int u = 0; u < 64; u++) {
            ushort4 h4 = *(const ushort4*)&xw_l[u][lane * 4];
            float4 xv = make_float4(bf2f(h4.x), bf2f(h4.y), bf2f(h4.z), bf2f(h4.w));
#pragma unroll
            for (int k = 0; k < 5; k++) {
                float wk = w_l[k][u][wv];
                acc[k].x = fmaf(wk, xv.x, acc[k].x);
                acc[k].y = fmaf(wk, xv.y, acc[k].y);
                acc[k].z = fmaf(wk, xv.z, acc[k].z);
                acc[k].w = fmaf(wk, xv.w, acc[k].w);
            }
        }

        float4 pA[5], pB[5];
#pragma unroll
        for (int n = 0; n < 5; n++) {
            pA[n] = *(const float4*)&ws[n * 256 + lane * 4];
            pB[n] = *(const float4*)&ws[1280 + n * 256 + lane * 4];
        }
        float pa2r[5], pb2r[5];
#pragma unroll
        for (int n = 0; n < 5; n++) { pa2r[n] = ws[2560 + n]; pb2r[n] = ws[2565 + n]; }

#pragma unroll
        for (int k = 0; k < 5; k++) {
            float4 o = acc[k];
            float r[11];
            r[0] = fmaf(o.x, o.x, fmaf(o.y, o.y, fmaf(o.z, o.z, o.w * o.w)));
#pragma unroll
            for (int n = 0; n < 5; n++) {
                float4 p = pA[n];
                r[1 + n] = fmaf(o.x, p.x, fmaf(o.y, p.y, fmaf(o.z, p.z, o.w * p.w)));
                float4 q = pB[n];
                r[6 + n] = fmaf(o.x, q.x, fmaf(o.y, q.y, fmaf(o.z, q.z, o.w * q.w)));
            }
#pragma unroll
            for (int off = 1; off < 64; off <<= 1) {
#pragma unroll
                for (int q = 0; q < 11; q++) r[q] += __shfl_xor(r[q], off);
            }
            if (lane == 0) {
                size_t idx = (((size_t)s * 5 + k) * 64 + v) * 5;
#pragma unroll
                for (int n = 0; n < 5; n++) {
                    da[idx + n] = r[0] - 2.f * r[1 + n] + pa2r[n];
                    db[idx + n] = r[0] - 2.f * r[6 + n] + pb2r[n];
                }
            }
        }
    }
}

// ================= K_C: softmax + store (x R_KC) ===========================
__global__ __launch_bounds__(320) void kC(const float* __restrict__ ws_in,
                                          float* __restrict__ out_in) {
    int bx = blockIdx.x;
    int s = bx >> 6, v1 = bx & 63;
    int t = threadIdx.x;
    int v2 = t / 5, k = t - v2 * 5;

    __shared__ float ob[1600];
    __shared__ float cvs[5];

#pragma unroll 1
    for (int rep = 0; rep < R_KC; rep++) {
        int oz = opaque_zero();
        const float* ws = ws_in + oz;
        float* out = out_in + oz;
        const float* da = ws + 1445888;
        const float* db = ws + 1497088;
        __syncthreads();
        if (t < 5) cvs[t] = ws[2570 + t];

        const float* dap = da + (((size_t)s * 5 + k) * 64 + v1) * 5;
        const float* dbp = db + (((size_t)s * 5 + k) * 64 + v2) * 5;
        float l0[5];
#pragma unroll
        for (int n = 0; n < 5; n++) l0[n] = dap[n] + dbp[n];
        __syncthreads();
        float m = -3.4e38f;
#pragma unroll
        for (int n = 0; n < 5; n++) { l0[n] += cvs[n]; m = fmaxf(m, l0[n]); }
        float e[5], sum = 0.f;
#pragma unroll
        for (int n = 0; n < 5; n++) { e[n] = __expf(l0[n] - m); sum += e[n]; }
        float r = 1.f / sum;
#pragma unroll
        for (int n = 0; n < 5; n++) ob[t * 5 + n] = e[n] * r;
        __syncthreads();

        const float4* ob4 = (const float4*)ob;
        float4* op = (float4*)(out + (size_t)bx * 1600);
        for (int i = t; i < 400; i += 320) op[i] = ob4[i];
    }
}

// ---------------- launch ----------------------------------------------------
extern "C" void kernel_launch(void* const* d_in, const int* in_sizes, int n_in,
                              void* d_out, int out_size, void* d_ws, size_t ws_size,
                              hipStream_t stream) {
    const float* sup_entities = (const float*)d_in[0];
    const float* sup_context  = (const float*)d_in[1];
    const float* x            = (const float*)d_in[2];
    const float* context      = (const float*)d_in[3];
    const float* W            = (const float*)d_in[4];
    const float* Wself        = (const float*)d_in[5];
    const int*   counts       = (const int*)d_in[6];
    float* out = (float*)d_out;
    float* ws = (float*)d_ws;

    k0_setup<<<15, 256, 0, stream>>>(sup_entities, sup_context, counts, ws);
    k2_w<<<SS * EE, 256, 0, stream>>>(context, ws);
    k1_gemm<<<256, 256, 0, stream>>>(x, W, Wself, ws);
    kB<<<512, 256, 0, stream>>>(ws);
    kC<<<SS * EE, 320, 0, stream>>>(ws, out);
}

// Round 10
// 117.210 us; speedup vs baseline: 4.4744x; 4.4744x over previous
//
#include <hip/hip_runtime.h>
#include <hip/hip_bf16.h>

#define SS 32
#define EE 64
#define DD 256
#define LL 5

typedef unsigned int uint32;

static __device__ __forceinline__ ushort f2bf(float f) {
    uint32 u = __float_as_uint(f);
    uint32 r = (u + 0x7FFFu + ((u >> 16) & 1u)) >> 16;   // RNE
    return (ushort)r;
}
static __device__ __forceinline__ float bf2f(ushort h) {
    return __uint_as_float(((uint32)h) << 16);
}

// DPP adds (VALU pipe). red16: 16-lane group sum. red64: full-wave sum into
// lane 63 (then readlane). Chain: xor1, xor2, xor7, xor15 -> row sums;
// row_bcast15 (0x142): lanes 16-31 += lane15, 48-63 += lane47;
// row_bcast31 (0x143): lanes 32-63 += lane31 -> lane63 = wave total.
template <int CTRL>
static __device__ __forceinline__ float dpp_add(float x) {
    int y = __builtin_amdgcn_update_dpp(0, __float_as_int(x), CTRL, 0xF, 0xF, true);
    return x + __int_as_float(y);
}
static __device__ __forceinline__ float red16(float x) {
    x = dpp_add<0xB1>(x);
    x = dpp_add<0x4E>(x);
    x = dpp_add<0x141>(x);
    x = dpp_add<0x140>(x);
    return x;
}
static __device__ __forceinline__ float red64_scalar(float x) {
    x = red16(x);
    x = dpp_add<0x142>(x);   // row_bcast15
    x = dpp_add<0x143>(x);   // row_bcast31
    return __uint_as_float((uint32)__builtin_amdgcn_readlane(__float_as_int(x), 63));
}

// ws layout (f32 units):
//   pa 0 (1280) | pb 1280 (1280) | pa2 2560(5) | pb2 2565(5) | cvec 2570(5)
//   xself 4096 (524288) | xw 528384 (bf16 x 524288)
//   wt 790528 (655360) [s][k][u][v] | da 1445888 | db 1497088

// ================= K2F: context stream (2048 blocks) + setup (10 blocks) ===
// Stream branch: R6-validated local cc recompute prologue + R8-validated
// DPP main loop (~110 live VGPR, pinned at 128 by waves_per_eu(4,4)).
// Setup branch (bx>=2048): pa/pb/pa2/pb2/cvec (tiny reg class, same pin ok).
__global__ __attribute__((amdgpu_waves_per_eu(4, 4))) __launch_bounds__(256)
void k2f(const float* __restrict__ context, const float* __restrict__ sup_context,
         const float* __restrict__ sup_entities, const int* __restrict__ counts,
         float* __restrict__ ws) {
    int bx = blockIdx.x;
    int t = threadIdx.x, lane = t & 63, wv = t >> 6;

    __shared__ float cc_l[1280];
    __shared__ float cc2_l[8];
    __shared__ float wbuf[5][64];
    __shared__ float part[4];

    if (bx >= 2048) {
        // ---------------- setup branch (10 blocks) ----------------
        int b = bx - 2048;
        int k = (b >= 5) ? b - 5 : b;
        int off = (b >= 5) ? 256 : 0;
        float s = 0.f;
#pragma unroll
        for (int j = 0; j < 5; j++) s += sup_entities[(k * 5 + j) * 512 + off + t];
        float m = s * 0.2f;
        ws[(b >= 5 ? 1280 : 0) + k * 256 + t] = m;
        float p = m * m;
#pragma unroll
        for (int o = 1; o < 64; o <<= 1) p += __shfl_xor(p, o);
        if (lane == 0) part[wv] = p;
        __syncthreads();
        if (t == 0) ws[2560 + b] = part[0] + part[1] + part[2] + part[3];
        if (b == 0 && t == 1) {
            float cnt[5], tot = 0.f;
#pragma unroll
            for (int q = 0; q < 5; q++) { cnt[q] = (float)counts[q] + 1.0f; tot += cnt[q]; }
#pragma unroll
            for (int q = 0; q < 5; q++) ws[2570 + q] = cnt[q] / (tot - cnt[q]);
        }
        return;
    }

    // ---------------- stream branch ----------------
    int s = bx >> 6, u = bx & 63;
    int g = lane >> 4, gl = lane & 15;
    int G = wv * 4 + g;   // 0..15

    // cc recompute (sup_context 25.6 KB, L2-hot; measured free in R6)
    for (int i = t; i < 1280; i += 256) {
        int k = i >> 8, d = i & 255;
        float sum = 0.f;
#pragma unroll
        for (int j = 0; j < 5; j++) sum += sup_context[(k * 5 + j) * DD + d];
        cc_l[i] = sum * 0.2f;
    }
    __syncthreads();
    if (t < 80) {
        int k = t >> 4, gg = t & 15;
        float p = 0.f;
#pragma unroll
        for (int j = 0; j < 16; j++) { float v = cc_l[k * 256 + gg * 16 + j]; p = fmaf(v, v, p); }
#pragma unroll
        for (int o = 1; o < 16; o <<= 1) p += __shfl_xor(p, o);
        if (gg == 0) cc2_l[k] = p;
    }
    __syncthreads();

    float4 cc[5][4];
    float cc2r[5];
#pragma unroll
    for (int k = 0; k < 5; k++) {
#pragma unroll
        for (int j = 0; j < 4; j++)
            cc[k][j] = *(const float4*)&cc_l[k * 256 + j * 64 + gl * 4];
        cc2r[k] = cc2_l[k];
    }

    float* wt = ws + 790528;
    const float* base = context + (size_t)bx * (EE * DD) + gl * 4;
#pragma unroll
    for (int p = 0; p < 4; p++) {
        int v = p * 16 + G;
        const float* row = base + v * DD;
        float4 a[4];
#pragma unroll
        for (int j = 0; j < 4; j++) a[j] = *(const float4*)&row[j * 64];

        float cn = 0.f;
        float cr[5] = {0.f, 0.f, 0.f, 0.f, 0.f};
#pragma unroll
        for (int j = 0; j < 4; j++) {
            float4 c4 = a[j];
            cn = fmaf(c4.x, c4.x, fmaf(c4.y, c4.y, fmaf(c4.z, c4.z, fmaf(c4.w, c4.w, cn))));
#pragma unroll
            for (int k = 0; k < 5; k++) {
                float4 pp = cc[k][j];
                cr[k] = fmaf(c4.x, pp.x, fmaf(c4.y, pp.y, fmaf(c4.z, pp.z, fmaf(c4.w, pp.w, cr[k]))));
            }
        }
        cn = red16(cn);
#pragma unroll
        for (int k = 0; k < 5; k++) cr[k] = red16(cr[k]);
        if (gl == 0) {
#pragma unroll
            for (int k = 0; k < 5; k++) {
                float d2 = cn - 2.f * cr[k] + cc2r[k];
                wbuf[k][v] = (u == v) ? 0.f : 1.f / fmaxf(d2, 1e-8f);
            }
        }
    }
    __syncthreads();
    for (int i = t; i < 320; i += 256) {   // two iterations: k=4 needs i>=256
        int k = i >> 6, v = i & 63;
        wt[(((size_t)s * 5 + k) * 64 + u) * 64 + v] = wbuf[k][v];
    }
}

// ================= K1: xW (bf16) and xself (f32) ===========================
// Unchanged (R6/R8-validated). waves_per_eu(2,2) pins 256-VGPR budget.
__global__ __attribute__((amdgpu_waves_per_eu(2, 2))) __launch_bounds__(256)
void k1_gemm(
    const float* __restrict__ x, const float* __restrict__ W,
    const float* __restrict__ Wself, float* __restrict__ ws) {
    float* xself = ws + 4096;
    ushort* xw = (ushort*)(ws + 528384);

    int row0 = blockIdx.x * 8;
    int t = threadIdx.x, lane = t & 63, wv = t >> 6;

    float xreg[8];
    const float* xbase = x + row0 * DD + wv * 64 + lane;
#pragma unroll
    for (int r = 0; r < 8; r++) xreg[r] = xbase[r * DD];

    float4 accW[8], accS[8];
#pragma unroll
    for (int r = 0; r < 8; r++) {
        accW[r] = make_float4(0.f, 0.f, 0.f, 0.f);
        accS[r] = make_float4(0.f, 0.f, 0.f, 0.f);
    }
    const float4* Wp  = ((const float4*)W) + lane;
    const float4* Wsp = ((const float4*)Wself) + lane;
#pragma unroll 2
    for (int i = 0; i < 64; i++) {
        int kk = wv * 64 + i;
        float4 w4  = Wp[kk * 64];
        float4 ws4 = Wsp[kk * 64];
#pragma unroll
        for (int r = 0; r < 8; r++) {
            float xs = __uint_as_float(
                (uint32)__builtin_amdgcn_readlane((int)__float_as_uint(xreg[r]), i));
            accW[r].x = fmaf(xs, w4.x, accW[r].x);
            accW[r].y = fmaf(xs, w4.y, accW[r].y);
            accW[r].z = fmaf(xs, w4.z, accW[r].z);
            accW[r].w = fmaf(xs, w4.w, accW[r].w);
            accS[r].x = fmaf(xs, ws4.x, accS[r].x);
            accS[r].y = fmaf(xs, ws4.y, accS[r].y);
            accS[r].z = fmaf(xs, ws4.z, accS[r].z);
            accS[r].w = fmaf(xs, ws4.w, accS[r].w);
        }
    }
    __shared__ float4 redbuf[4][8][64];   // 32 KB
#pragma unroll
    for (int r = 0; r < 8; r++) redbuf[wv][r][lane] = accS[r];
    __syncthreads();
    {
        int r = t >> 5;
#pragma unroll
        for (int f = 0; f < 2; f++) {
            int l4 = (t & 31) + 32 * f;
            float4 a = redbuf[0][r][l4], b = redbuf[1][r][l4];
            float4 c = redbuf[2][r][l4], d = redbuf[3][r][l4];
            float4 s4 = make_float4(a.x + b.x + c.x + d.x, a.y + b.y + c.y + d.y,
                                    a.z + b.z + c.z + d.z, a.w + b.w + c.w + d.w);
            *(float4*)&xself[(row0 + r) * DD + l4 * 4] = s4;
        }
    }
    __syncthreads();
#pragma unroll
    for (int r = 0; r < 8; r++) redbuf[wv][r][lane] = accW[r];
    __syncthreads();
    {
        int r = t >> 5;
#pragma unroll
        for (int f = 0; f < 2; f++) {
            int l4 = (t & 31) + 32 * f;
            float4 a = redbuf[0][r][l4], b = redbuf[1][r][l4];
            float4 c = redbuf[2][r][l4], d = redbuf[3][r][l4];
            float4 s4 = make_float4(a.x + b.x + c.x + d.x, a.y + b.y + c.y + d.y,
                                    a.z + b.z + c.z + d.z, a.w + b.w + c.w + d.w);
            ushort4 h;
            h.x = f2bf(s4.x); h.y = f2bf(s4.y); h.z = f2bf(s4.z); h.w = f2bf(s4.w);
            *(ushort4*)&xw[(row0 + r) * DD + l4 * 4] = h;
        }
    }
}

// ================= K_B: out + distance dots — DS-light rewrite =============
// R9 diagnosis: old kB spent 330 DS ops/thread in the shfl epilogue + 320 LDS
// reads for w. Now: w in registers (u=lane), fetched via v_readlane with
// compile-time index (full unroll); epilogue reduced with DPP (VALU) + one
// readlane — ZERO DS ops outside the xw staging + 64 b64 reads.
__global__ __attribute__((amdgpu_waves_per_eu(2, 2))) __launch_bounds__(256)
void kB(const float* __restrict__ ws) {
    const ushort* xw = (const ushort*)(ws + 528384);
    const float* xself = ws + 4096;
    const float* wt = ws + 790528;
    float* da = (float*)(ws + 1445888);
    float* db = (float*)(ws + 1497088);

    int bx = blockIdx.x;
    int s = bx >> 4, vg = bx & 15;
    int t = threadIdx.x, lane = t & 63, wv = t >> 6;
    int v = vg * 4 + wv;

    __shared__ ushort xw_l[64][256];   // 32 KB

    // w(k, u=lane) into registers (stride-64 gather, L2/L3-hot, issued early)
    float wreg[5];
#pragma unroll
    for (int k = 0; k < 5; k++)
        wreg[k] = wt[(((size_t)s * 5 + k) * 64 + lane) * 64 + v];

    {   // stage xw slab (contiguous 32 KB, coalesced)
        const uint4* src = (const uint4*)(xw + (size_t)s * (EE * DD));
        uint4* dst = (uint4*)&xw_l[0][0];
#pragma unroll
        for (int j = 0; j < 8; j++) dst[j * 256 + t] = src[j * 256 + t];
    }

    float4 acc[5];
    {
        float4 xs = *(const float4*)&xself[((size_t)s * 64 + v) * DD + lane * 4];
#pragma unroll
        for (int k = 0; k < 5; k++) acc[k] = xs;
    }
    __syncthreads();

#pragma unroll
    for (int u = 0; u < 64; u++) {
        ushort4 h4 = *(const ushort4*)&xw_l[u][lane * 4];
        float4 xv = make_float4(bf2f(h4.x), bf2f(h4.y), bf2f(h4.z), bf2f(h4.w));
#pragma unroll
        for (int k = 0; k < 5; k++) {
            float wk = __uint_as_float(
                (uint32)__builtin_amdgcn_readlane(__float_as_int(wreg[k]), u));
            acc[k].x = fmaf(wk, xv.x, acc[k].x);
            acc[k].y = fmaf(wk, xv.y, acc[k].y);
            acc[k].z = fmaf(wk, xv.z, acc[k].z);
            acc[k].w = fmaf(wk, xv.w, acc[k].w);
        }
    }

    float4 pA[5], pB[5];
#pragma unroll
    for (int n = 0; n < 5; n++) {
        pA[n] = *(const float4*)&ws[n * 256 + lane * 4];
        pB[n] = *(const float4*)&ws[1280 + n * 256 + lane * 4];
    }
    float pa2r[5], pb2r[5];
#pragma unroll
    for (int n = 0; n < 5; n++) { pa2r[n] = ws[2560 + n]; pb2r[n] = ws[2565 + n]; }

#pragma unroll
    for (int k = 0; k < 5; k++) {
        float4 o = acc[k];
        float r[11];
        r[0] = fmaf(o.x, o.x, fmaf(o.y, o.y, fmaf(o.z, o.z, o.w * o.w)));
#pragma unroll
        for (int n = 0; n < 5; n++) {
            float4 p = pA[n];
            r[1 + n] = fmaf(o.x, p.x, fmaf(o.y, p.y, fmaf(o.z, p.z, o.w * p.w)));
            float4 q = pB[n];
            r[6 + n] = fmaf(o.x, q.x, fmaf(o.y, q.y, fmaf(o.z, q.z, o.w * q.w)));
        }
        float tot[11];
#pragma unroll
        for (int q = 0; q < 11; q++) tot[q] = red64_scalar(r[q]);
        if (lane == 0) {
            size_t idx = (((size_t)s * 5 + k) * 64 + v) * 5;
#pragma unroll
            for (int n = 0; n < 5; n++) {
                da[idx + n] = tot[0] - 2.f * tot[1 + n] + pa2r[n];
                db[idx + n] = tot[0] - 2.f * tot[6 + n] + pb2r[n];
            }
        }
    }
}

// ================= K_C: logits + softmax + coalesced store ==================
__global__ __launch_bounds__(320) void kC(const float* __restrict__ ws,
                                          float* __restrict__ out) {
    const float* da = ws + 1445888;
    const float* db = ws + 1497088;
    int bx = blockIdx.x;
    int s = bx >> 6, v1 = bx & 63;
    int t = threadIdx.x;
    int v2 = t / 5, k = t - v2 * 5;

    __shared__ float ob[1600];
    __shared__ float cvs[5];
    if (t < 5) cvs[t] = ws[2570 + t];

    const float* dap = da + (((size_t)s * 5 + k) * 64 + v1) * 5;
    const float* dbp = db + (((size_t)s * 5 + k) * 64 + v2) * 5;
    float l0[5];
#pragma unroll
    for (int n = 0; n < 5; n++) l0[n] = dap[n] + dbp[n];
    __syncthreads();
    float m = -3.4e38f;
#pragma unroll
    for (int n = 0; n < 5; n++) { l0[n] += cvs[n]; m = fmaxf(m, l0[n]); }
    float e[5], sum = 0.f;
#pragma unroll
    for (int n = 0; n < 5; n++) { e[n] = __expf(l0[n] - m); sum += e[n]; }
    float r = 1.f / sum;
#pragma unroll
    for (int n = 0; n < 5; n++) ob[t * 5 + n] = e[n] * r;
    __syncthreads();

    const float4* ob4 = (const float4*)ob;
    float4* op = (float4*)(out + (size_t)bx * 1600);
    for (int i = t; i < 400; i += 320) op[i] = ob4[i];
}

// ---------------- launch ----------------------------------------------------
extern "C" void kernel_launch(void* const* d_in, const int* in_sizes, int n_in,
                              void* d_out, int out_size, void* d_ws, size_t ws_size,
                              hipStream_t stream) {
    const float* sup_entities = (const float*)d_in[0];
    const float* sup_context  = (const float*)d_in[1];
    const float* x            = (const float*)d_in[2];
    const float* context      = (const float*)d_in[3];
    const float* W            = (const float*)d_in[4];
    const float* Wself        = (const float*)d_in[5];
    const int*   counts       = (const int*)d_in[6];
    float* out = (float*)d_out;
    float* ws = (float*)d_ws;

    k2f<<<SS * EE + 10, 256, 0, stream>>>(context, sup_context, sup_entities, counts, ws);
    k1_gemm<<<256, 256, 0, stream>>>(x, W, Wself, ws);
    kB<<<512, 256, 0, stream>>>(ws);
    kC<<<SS * EE, 320, 0, stream>>>(ws, out);
}